// Round 1
// 1379.219 us; speedup vs baseline: 2.5814x; 2.5814x over previous
//
#include <hip/hip_runtime.h>
#include <stdint.h>
#include <stddef.h>

// W4A8 fake-quant SwiGLU MLP for MI355X (gfx950).
// Exact-integer reformulation: fake-quant values are int*scale, so every
// matmul is an int8 x int4 integer GEMM (exact in i32/f32) times rank-1 scales.
// GEMMs: mfma_i32_16x16x64_i8, 128x128 tiles, global_load_lds width-16,
// XOR-swizzled LDS (slot = (quad + (row>>1)) & 3) for conflict-free b128 reads.
// No atomics: h row-absmax is recomputed in quant_h (two-pass over the row).
//
// R1 fix: gemm1 was compiled under __launch_bounds__(256,4) => 128-VGPR cap,
// but accg+accu alone need 128 VGPRs -> accumulators spilled to scratch
// (rocprof: WRITE_SIZE 6.2 GB vs 180 MB legit, FETCH==WRITE, VGPR_Count=64,
// MfmaUtil 5.8%). Relax to (256,2) -> 256-VGPR budget, no spill.

using i32x4 = __attribute__((ext_vector_type(4))) int;

#define BM 128
#define BN 128
#define BK 64

__device__ __forceinline__ void gl2lds16(const void* gptr, void* lptr) {
  __builtin_amdgcn_global_load_lds(
      (const __attribute__((address_space(1))) uint32_t*)gptr,
      (__attribute__((address_space(3))) uint32_t*)lptr, 16, 0, 0);
}

// Per-row symmetric fake-quant: scale = max(absmax/qmax, 1e-8),
// q = clip(rintf(v/scale), qmin, qmax). rintf == RNE == jnp.round.
__global__ void quant_rows_kernel(const float* __restrict__ src,
                                  int8_t* __restrict__ dst,
                                  float* __restrict__ scales,
                                  int cols, float qmax, float qmin) {
  const int row = blockIdx.x;
  const int n4 = cols >> 2;
  const float4* s4 = (const float4*)(src + (size_t)row * cols);
  float amax = 0.0f;
  for (int i = threadIdx.x; i < n4; i += blockDim.x) {
    float4 v = s4[i];
    amax = fmaxf(amax, fmaxf(fmaxf(fabsf(v.x), fabsf(v.y)),
                             fmaxf(fabsf(v.z), fabsf(v.w))));
  }
#pragma unroll
  for (int off = 32; off > 0; off >>= 1)
    amax = fmaxf(amax, __shfl_xor(amax, off, 64));
  __shared__ float wmax[4];
  if ((threadIdx.x & 63) == 0) wmax[threadIdx.x >> 6] = amax;
  __syncthreads();
  const float scale =
      fmaxf(fmaxf(fmaxf(wmax[0], wmax[1]), fmaxf(wmax[2], wmax[3])) / qmax,
            1e-8f);
  if (threadIdx.x == 0) scales[row] = scale;
  char4* d4 = (char4*)(dst + (size_t)row * cols);
  for (int i = threadIdx.x; i < n4; i += blockDim.x) {
    float4 v = s4[i];
    char4 q;
    q.x = (char)(int)fminf(fmaxf(rintf(v.x / scale), qmin), qmax);
    q.y = (char)(int)fminf(fmaxf(rintf(v.y / scale), qmin), qmax);
    q.z = (char)(int)fminf(fmaxf(rintf(v.z / scale), qmin), qmax);
    q.w = (char)(int)fminf(fmaxf(rintf(v.w / scale), qmin), qmax);
    d4[i] = q;
  }
}

// Two-pass per-row quant of h: pass1 block-reduce absmax, pass2 quantize.
// Also writes sh[row] for gemm2's epilogue. No atomics anywhere.
__global__ void quant_h_kernel(const float* __restrict__ h,
                               int8_t* __restrict__ hq,
                               float* __restrict__ sh, int cols) {
  const int row = blockIdx.x;
  const int n4 = cols >> 2;
  const float4* s4 = (const float4*)(h + (size_t)row * cols);
  float amax = 0.0f;
  for (int i = threadIdx.x; i < n4; i += blockDim.x) {
    float4 v = s4[i];
    amax = fmaxf(amax, fmaxf(fmaxf(fabsf(v.x), fabsf(v.y)),
                             fmaxf(fabsf(v.z), fabsf(v.w))));
  }
#pragma unroll
  for (int off = 32; off > 0; off >>= 1)
    amax = fmaxf(amax, __shfl_xor(amax, off, 64));
  __shared__ float wmax[4];
  if ((threadIdx.x & 63) == 0) wmax[threadIdx.x >> 6] = amax;
  __syncthreads();
  const float scale =
      fmaxf(fmaxf(fmaxf(wmax[0], wmax[1]), fmaxf(wmax[2], wmax[3])) / 127.0f,
            1e-8f);
  if (threadIdx.x == 0) sh[row] = scale;
  char4* d4 = (char4*)(hq + (size_t)row * cols);
  for (int i = threadIdx.x; i < n4; i += blockDim.x) {
    float4 v = s4[i];
    char4 q;
    q.x = (char)(int)fminf(fmaxf(rintf(v.x / scale), -128.0f), 127.0f);
    q.y = (char)(int)fminf(fmaxf(rintf(v.y / scale), -128.0f), 127.0f);
    q.z = (char)(int)fminf(fmaxf(rintf(v.z / scale), -128.0f), 127.0f);
    q.w = (char)(int)fminf(fmaxf(rintf(v.w / scale), -128.0f), 127.0f);
    d4[i] = q;
  }
}

// Fused gate+up GEMM: acc_g = xq @ Wg^T, acc_u = xq @ Wu^T (int32 exact),
// epilogue h = silu(acc_g*sx*swg) * (acc_u*sx*swu) -> hbuf (f32).
// __launch_bounds__(256, 2): 256-VGPR budget; accg+accu (128 VGPR) + af +
// addressing fit without spilling. (256,4) capped at 128 VGPR and spilled
// the accumulators to scratch -> 12 GB of HBM scratch traffic per dispatch.
__global__ __launch_bounds__(256, 2) void gemm1_kernel(
    const int8_t* __restrict__ xq, const int8_t* __restrict__ wgq,
    const int8_t* __restrict__ wuq, const float* __restrict__ sx,
    const float* __restrict__ swg, const float* __restrict__ swu,
    float* __restrict__ hbuf, int M, int N, int K) {
  __shared__ __align__(16) int8_t sA[BM * BK];
  __shared__ __align__(16) int8_t sBg[BN * BK];
  __shared__ __align__(16) int8_t sBu[BN * BK];

  const int tid = threadIdx.x;
  const int lane = tid & 63;
  const int quad = lane >> 4;
  const int l16 = lane & 15;
  const int wave = tid >> 6;
  const int wm = wave >> 1;
  const int wn = wave & 1;
  const int m0 = blockIdx.y * BM;
  const int n0 = blockIdx.x * BN;

  i32x4 accg[4][4] = {};
  i32x4 accu[4][4] = {};

  for (int k0 = 0; k0 < K; k0 += BK) {
#pragma unroll
    for (int it = 0; it < 2; ++it) {
      const int c = tid + it * 256;   // 512 16B chunks per 128x64 tile
      const int r = c >> 2;           // tile row
      const int s = c & 3;            // LDS slot within row
      const int kc = ((s - (r >> 1)) & 3) << 4;  // XOR-swizzled source chunk
      gl2lds16(xq  + (size_t)(m0 + r) * K + (k0 + kc), sA  + c * 16);
      gl2lds16(wgq + (size_t)(n0 + r) * K + (k0 + kc), sBg + c * 16);
      gl2lds16(wuq + (size_t)(n0 + r) * K + (k0 + kc), sBu + c * 16);
    }
    __syncthreads();

    i32x4 af[4];
#pragma unroll
    for (int i = 0; i < 4; ++i) {
      const int ar = wm * 64 + i * 16 + l16;
      af[i] = *(const i32x4*)(sA + ar * BK + (((quad + (ar >> 1)) & 3) << 4));
    }
#pragma unroll
    for (int j = 0; j < 4; ++j) {
      const int br = wn * 64 + j * 16 + l16;
      const int bo = br * BK + (((quad + (br >> 1)) & 3) << 4);
      i32x4 bg = *(const i32x4*)(sBg + bo);
      i32x4 bu = *(const i32x4*)(sBu + bo);
#pragma unroll
      for (int i = 0; i < 4; ++i) {
        accg[i][j] = __builtin_amdgcn_mfma_i32_16x16x64_i8(af[i], bg, accg[i][j], 0, 0, 0);
        accu[i][j] = __builtin_amdgcn_mfma_i32_16x16x64_i8(af[i], bu, accu[i][j], 0, 0, 0);
      }
    }
    __syncthreads();
  }

  float sg[4], su[4];
#pragma unroll
  for (int j = 0; j < 4; ++j) {
    const int col = n0 + wn * 64 + j * 16 + l16;
    sg[j] = swg[col];
    su[j] = swu[col];
  }
#pragma unroll
  for (int i = 0; i < 4; ++i) {
#pragma unroll
    for (int r = 0; r < 4; ++r) {
      const int row = m0 + wm * 64 + i * 16 + quad * 4 + r;
      const float s_x = sx[row];
#pragma unroll
      for (int j = 0; j < 4; ++j) {
        const int col = n0 + wn * 64 + j * 16 + l16;
        const float g = (float)accg[i][j][r] * s_x * sg[j];
        const float u = (float)accu[i][j][r] * s_x * su[j];
        hbuf[(size_t)row * N + col] = (g / (1.0f + expf(-g))) * u;  // silu(g)*u
      }
    }
  }
}

// Down-projection GEMM: out = (hq @ Wd^T) * sh[m] * swd[n]
// acc[4][4] = 64 VGPRs -> fits comfortably under the 128-VGPR cap of (256,4).
__global__ __launch_bounds__(256, 4) void gemm2_kernel(
    const int8_t* __restrict__ hq, const int8_t* __restrict__ wdq,
    const float* __restrict__ sh, const float* __restrict__ swd,
    float* __restrict__ out, int M, int N, int K) {
  __shared__ __align__(16) int8_t sA[BM * BK];
  __shared__ __align__(16) int8_t sB[BN * BK];

  const int tid = threadIdx.x;
  const int lane = tid & 63;
  const int quad = lane >> 4;
  const int l16 = lane & 15;
  const int wave = tid >> 6;
  const int wm = wave >> 1;
  const int wn = wave & 1;
  const int m0 = blockIdx.y * BM;
  const int n0 = blockIdx.x * BN;

  i32x4 acc[4][4] = {};

  for (int k0 = 0; k0 < K; k0 += BK) {
#pragma unroll
    for (int it = 0; it < 2; ++it) {
      const int c = tid + it * 256;
      const int r = c >> 2;
      const int s = c & 3;
      const int kc = ((s - (r >> 1)) & 3) << 4;
      gl2lds16(hq  + (size_t)(m0 + r) * K + (k0 + kc), sA + c * 16);
      gl2lds16(wdq + (size_t)(n0 + r) * K + (k0 + kc), sB + c * 16);
    }
    __syncthreads();

    i32x4 af[4];
#pragma unroll
    for (int i = 0; i < 4; ++i) {
      const int ar = wm * 64 + i * 16 + l16;
      af[i] = *(const i32x4*)(sA + ar * BK + (((quad + (ar >> 1)) & 3) << 4));
    }
#pragma unroll
    for (int j = 0; j < 4; ++j) {
      const int br = wn * 64 + j * 16 + l16;
      i32x4 bf = *(const i32x4*)(sB + br * BK + (((quad + (br >> 1)) & 3) << 4));
#pragma unroll
      for (int i = 0; i < 4; ++i)
        acc[i][j] = __builtin_amdgcn_mfma_i32_16x16x64_i8(af[i], bf, acc[i][j], 0, 0, 0);
    }
    __syncthreads();
  }

  float sn[4];
#pragma unroll
  for (int j = 0; j < 4; ++j) sn[j] = swd[n0 + wn * 64 + j * 16 + l16];
#pragma unroll
  for (int i = 0; i < 4; ++i) {
#pragma unroll
    for (int r = 0; r < 4; ++r) {
      const int row = m0 + wm * 64 + i * 16 + quad * 4 + r;
      const float s_m = sh[row];
#pragma unroll
      for (int j = 0; j < 4; ++j) {
        const int col = n0 + wn * 64 + j * 16 + l16;
        out[(size_t)row * N + col] = (float)acc[i][j][r] * s_m * sn[j];
      }
    }
  }
}

extern "C" void kernel_launch(void* const* d_in, const int* in_sizes, int n_in,
                              void* d_out, int out_size, void* d_ws, size_t ws_size,
                              hipStream_t stream) {
  const float* x  = (const float*)d_in[0];   // [2,2048,4096]
  const float* Wg = (const float*)d_in[1];   // [11008,4096]
  const float* Wu = (const float*)d_in[2];   // [11008,4096]
  const float* Wd = (const float*)d_in[3];   // [4096,11008]
  float* out = (float*)d_out;                // [2,2048,4096] f32

  const int M = 4096;   // B*S
  const int D = 4096;
  const int F = 11008;

  // workspace layout (~378 MB total), all offsets 16B-aligned
  uint8_t* ws = (uint8_t*)d_ws;
  size_t off = 0;
  int8_t* xq  = (int8_t*)(ws + off); off += (size_t)M * D;      // 16 MB
  int8_t* wgq = (int8_t*)(ws + off); off += (size_t)F * D;      // 45 MB
  int8_t* wuq = (int8_t*)(ws + off); off += (size_t)F * D;      // 45 MB
  int8_t* wdq = (int8_t*)(ws + off); off += (size_t)D * F;      // 45 MB
  int8_t* hq  = (int8_t*)(ws + off); off += (size_t)M * F;      // 45 MB
  float* hbuf = (float*)(ws + off);  off += (size_t)M * F * 4;  // 180 MB
  float* sx   = (float*)(ws + off);  off += (size_t)M * 4;
  float* swg  = (float*)(ws + off);  off += (size_t)F * 4;
  float* swu  = (float*)(ws + off);  off += (size_t)F * 4;
  float* swd  = (float*)(ws + off);  off += (size_t)D * 4;
  float* sh   = (float*)(ws + off);  off += (size_t)M * 4;

  hipLaunchKernelGGL(quant_rows_kernel, dim3(M), dim3(256), 0, stream,
                     x, xq, sx, D, 127.0f, -128.0f);
  hipLaunchKernelGGL(quant_rows_kernel, dim3(F), dim3(256), 0, stream,
                     Wg, wgq, swg, D, 7.0f, -8.0f);
  hipLaunchKernelGGL(quant_rows_kernel, dim3(F), dim3(256), 0, stream,
                     Wu, wuq, swu, D, 7.0f, -8.0f);
  hipLaunchKernelGGL(quant_rows_kernel, dim3(D), dim3(256), 0, stream,
                     Wd, wdq, swd, F, 7.0f, -8.0f);
  hipLaunchKernelGGL(gemm1_kernel, dim3(F / BN, M / BM), dim3(256), 0, stream,
                     xq, wgq, wuq, sx, swg, swu, hbuf, M, F, D);
  hipLaunchKernelGGL(quant_h_kernel, dim3(M), dim3(256), 0, stream,
                     hbuf, hq, sh, F);
  hipLaunchKernelGGL(gemm2_kernel, dim3(D / BN, M / BM), dim3(256), 0, stream,
                     hq, wdq, sh, swd, out, M, D, F);
}

// Round 2
// 1378.835 us; speedup vs baseline: 2.5821x; 1.0003x over previous
//
#include <hip/hip_runtime.h>
#include <stdint.h>
#include <stddef.h>

// W4A8 fake-quant SwiGLU MLP for MI355X (gfx950).
// Exact-integer reformulation: fake-quant values are int*scale, so every
// matmul is an int8 x int4 integer GEMM (exact in i32/f32) times rank-1 scales.
// GEMMs: mfma_i32_16x16x64_i8, 128x128 tiles, global_load_lds width-16,
// XOR-swizzled LDS (slot = (quad + (row>>1)) & 3) for conflict-free b128 reads.
// No atomics: h row-absmax is recomputed in quant_h (two-pass over the row).
//
// R1: gemm1 (256,4)->(256,2): accumulator spill eliminated (12 GB scratch
//     traffic -> 0), 2700 -> 527 us.
// R2: (a) gemm2 had the SAME launch-bounds spill bug (acc 64 + addr ~130 regs
//     vs 128-reg cap of (256,4)) -> relax to (256,2).
//     (b) T1 bijective XCD swizzle on both GEMM grids (nwg%8==0 for both):
//     each XCD gets a contiguous m-chunk -> xq/hq rows L2-resident, weight
//     panels L3-resident. gemm1 FETCH was 1.5 GB vs 106 MB working set.

using i32x4 = __attribute__((ext_vector_type(4))) int;

#define BM 128
#define BN 128
#define BK 64

__device__ __forceinline__ void gl2lds16(const void* gptr, void* lptr) {
  __builtin_amdgcn_global_load_lds(
      (const __attribute__((address_space(1))) uint32_t*)gptr,
      (__attribute__((address_space(3))) uint32_t*)lptr, 16, 0, 0);
}

// Per-row symmetric fake-quant: scale = max(absmax/qmax, 1e-8),
// q = clip(rintf(v/scale), qmin, qmax). rintf == RNE == jnp.round.
__global__ void quant_rows_kernel(const float* __restrict__ src,
                                  int8_t* __restrict__ dst,
                                  float* __restrict__ scales,
                                  int cols, float qmax, float qmin) {
  const int row = blockIdx.x;
  const int n4 = cols >> 2;
  const float4* s4 = (const float4*)(src + (size_t)row * cols);
  float amax = 0.0f;
  for (int i = threadIdx.x; i < n4; i += blockDim.x) {
    float4 v = s4[i];
    amax = fmaxf(amax, fmaxf(fmaxf(fabsf(v.x), fabsf(v.y)),
                             fmaxf(fabsf(v.z), fabsf(v.w))));
  }
#pragma unroll
  for (int off = 32; off > 0; off >>= 1)
    amax = fmaxf(amax, __shfl_xor(amax, off, 64));
  __shared__ float wmax[4];
  if ((threadIdx.x & 63) == 0) wmax[threadIdx.x >> 6] = amax;
  __syncthreads();
  const float scale =
      fmaxf(fmaxf(fmaxf(wmax[0], wmax[1]), fmaxf(wmax[2], wmax[3])) / qmax,
            1e-8f);
  if (threadIdx.x == 0) scales[row] = scale;
  char4* d4 = (char4*)(dst + (size_t)row * cols);
  for (int i = threadIdx.x; i < n4; i += blockDim.x) {
    float4 v = s4[i];
    char4 q;
    q.x = (char)(int)fminf(fmaxf(rintf(v.x / scale), qmin), qmax);
    q.y = (char)(int)fminf(fmaxf(rintf(v.y / scale), qmin), qmax);
    q.z = (char)(int)fminf(fmaxf(rintf(v.z / scale), qmin), qmax);
    q.w = (char)(int)fminf(fmaxf(rintf(v.w / scale), qmin), qmax);
    d4[i] = q;
  }
}

// Two-pass per-row quant of h: pass1 block-reduce absmax, pass2 quantize
// (pass2 re-read is L1/L2-hot: one row = 43 KB). Writes sh[row] for gemm2.
__global__ void quant_h_kernel(const float* __restrict__ h,
                               int8_t* __restrict__ hq,
                               float* __restrict__ sh, int cols) {
  const int row = blockIdx.x;
  const int n4 = cols >> 2;
  const float4* s4 = (const float4*)(h + (size_t)row * cols);
  float amax = 0.0f;
  for (int i = threadIdx.x; i < n4; i += blockDim.x) {
    float4 v = s4[i];
    amax = fmaxf(amax, fmaxf(fmaxf(fabsf(v.x), fabsf(v.y)),
                             fmaxf(fabsf(v.z), fabsf(v.w))));
  }
#pragma unroll
  for (int off = 32; off > 0; off >>= 1)
    amax = fmaxf(amax, __shfl_xor(amax, off, 64));
  __shared__ float wmax[4];
  if ((threadIdx.x & 63) == 0) wmax[threadIdx.x >> 6] = amax;
  __syncthreads();
  const float scale =
      fmaxf(fmaxf(fmaxf(wmax[0], wmax[1]), fmaxf(wmax[2], wmax[3])) / 127.0f,
            1e-8f);
  if (threadIdx.x == 0) sh[row] = scale;
  char4* d4 = (char4*)(hq + (size_t)row * cols);
  for (int i = threadIdx.x; i < n4; i += blockDim.x) {
    float4 v = s4[i];
    char4 q;
    q.x = (char)(int)fminf(fmaxf(rintf(v.x / scale), -128.0f), 127.0f);
    q.y = (char)(int)fminf(fmaxf(rintf(v.y / scale), -128.0f), 127.0f);
    q.z = (char)(int)fminf(fmaxf(rintf(v.z / scale), -128.0f), 127.0f);
    q.w = (char)(int)fminf(fmaxf(rintf(v.w / scale), -128.0f), 127.0f);
    d4[i] = q;
  }
}

// Bijective XCD-aware remap of the linear block id (requires nwg % 8 == 0).
// XCD k (original lid % 8) receives the contiguous chunk [k*cpx, (k+1)*cpx).
__device__ __forceinline__ int xcd_swizzle(int lid, int nwg) {
  const int cpx = nwg >> 3;
  return (lid & 7) * cpx + (lid >> 3);
}

// Fused gate+up GEMM: acc_g = xq @ Wg^T, acc_u = xq @ Wu^T (int32 exact),
// epilogue h = silu(acc_g*sx*swg) * (acc_u*sx*swu) -> hbuf (f32).
// (256,2): 256-VGPR budget; accg+accu (128) + af + addressing fit, no spill.
__global__ __launch_bounds__(256, 2) void gemm1_kernel(
    const int8_t* __restrict__ xq, const int8_t* __restrict__ wgq,
    const int8_t* __restrict__ wuq, const float* __restrict__ sx,
    const float* __restrict__ swg, const float* __restrict__ swu,
    float* __restrict__ hbuf, int M, int N, int K) {
  __shared__ __align__(16) int8_t sA[BM * BK];
  __shared__ __align__(16) int8_t sBg[BN * BK];
  __shared__ __align__(16) int8_t sBu[BN * BK];

  const int tid = threadIdx.x;
  const int lane = tid & 63;
  const int quad = lane >> 4;
  const int l16 = lane & 15;
  const int wave = tid >> 6;
  const int wm = wave >> 1;
  const int wn = wave & 1;

  const int nwg = gridDim.x * gridDim.y;
  const int lid = xcd_swizzle(blockIdx.y * gridDim.x + blockIdx.x, nwg);
  const int n0 = (lid % gridDim.x) * BN;
  const int m0 = (lid / gridDim.x) * BM;

  i32x4 accg[4][4] = {};
  i32x4 accu[4][4] = {};

  for (int k0 = 0; k0 < K; k0 += BK) {
#pragma unroll
    for (int it = 0; it < 2; ++it) {
      const int c = tid + it * 256;   // 512 16B chunks per 128x64 tile
      const int r = c >> 2;           // tile row
      const int s = c & 3;            // LDS slot within row
      const int kc = ((s - (r >> 1)) & 3) << 4;  // XOR-swizzled source chunk
      gl2lds16(xq  + (size_t)(m0 + r) * K + (k0 + kc), sA  + c * 16);
      gl2lds16(wgq + (size_t)(n0 + r) * K + (k0 + kc), sBg + c * 16);
      gl2lds16(wuq + (size_t)(n0 + r) * K + (k0 + kc), sBu + c * 16);
    }
    __syncthreads();

    i32x4 af[4];
#pragma unroll
    for (int i = 0; i < 4; ++i) {
      const int ar = wm * 64 + i * 16 + l16;
      af[i] = *(const i32x4*)(sA + ar * BK + (((quad + (ar >> 1)) & 3) << 4));
    }
#pragma unroll
    for (int j = 0; j < 4; ++j) {
      const int br = wn * 64 + j * 16 + l16;
      const int bo = br * BK + (((quad + (br >> 1)) & 3) << 4);
      i32x4 bg = *(const i32x4*)(sBg + bo);
      i32x4 bu = *(const i32x4*)(sBu + bo);
#pragma unroll
      for (int i = 0; i < 4; ++i) {
        accg[i][j] = __builtin_amdgcn_mfma_i32_16x16x64_i8(af[i], bg, accg[i][j], 0, 0, 0);
        accu[i][j] = __builtin_amdgcn_mfma_i32_16x16x64_i8(af[i], bu, accu[i][j], 0, 0, 0);
      }
    }
    __syncthreads();
  }

  float sg[4], su[4];
#pragma unroll
  for (int j = 0; j < 4; ++j) {
    const int col = n0 + wn * 64 + j * 16 + l16;
    sg[j] = swg[col];
    su[j] = swu[col];
  }
#pragma unroll
  for (int i = 0; i < 4; ++i) {
#pragma unroll
    for (int r = 0; r < 4; ++r) {
      const int row = m0 + wm * 64 + i * 16 + quad * 4 + r;
      const float s_x = sx[row];
#pragma unroll
      for (int j = 0; j < 4; ++j) {
        const int col = n0 + wn * 64 + j * 16 + l16;
        const float g = (float)accg[i][j][r] * s_x * sg[j];
        const float u = (float)accu[i][j][r] * s_x * su[j];
        hbuf[(size_t)row * N + col] = (g / (1.0f + expf(-g))) * u;  // silu(g)*u
      }
    }
  }
}

// Down-projection GEMM: out = (hq @ Wd^T) * sh[m] * swd[n]
// (256,2): acc(64) + frags + addressing ~130-140 regs exceeded the 128-reg
// cap of (256,4) -> partial accumulator spill. Relaxed like gemm1.
__global__ __launch_bounds__(256, 2) void gemm2_kernel(
    const int8_t* __restrict__ hq, const int8_t* __restrict__ wdq,
    const float* __restrict__ sh, const float* __restrict__ swd,
    float* __restrict__ out, int M, int N, int K) {
  __shared__ __align__(16) int8_t sA[BM * BK];
  __shared__ __align__(16) int8_t sB[BN * BK];

  const int tid = threadIdx.x;
  const int lane = tid & 63;
  const int quad = lane >> 4;
  const int l16 = lane & 15;
  const int wave = tid >> 6;
  const int wm = wave >> 1;
  const int wn = wave & 1;

  const int nwg = gridDim.x * gridDim.y;
  const int lid = xcd_swizzle(blockIdx.y * gridDim.x + blockIdx.x, nwg);
  const int n0 = (lid % gridDim.x) * BN;
  const int m0 = (lid / gridDim.x) * BM;

  i32x4 acc[4][4] = {};

  for (int k0 = 0; k0 < K; k0 += BK) {
#pragma unroll
    for (int it = 0; it < 2; ++it) {
      const int c = tid + it * 256;
      const int r = c >> 2;
      const int s = c & 3;
      const int kc = ((s - (r >> 1)) & 3) << 4;
      gl2lds16(hq  + (size_t)(m0 + r) * K + (k0 + kc), sA + c * 16);
      gl2lds16(wdq + (size_t)(n0 + r) * K + (k0 + kc), sB + c * 16);
    }
    __syncthreads();

    i32x4 af[4];
#pragma unroll
    for (int i = 0; i < 4; ++i) {
      const int ar = wm * 64 + i * 16 + l16;
      af[i] = *(const i32x4*)(sA + ar * BK + (((quad + (ar >> 1)) & 3) << 4));
    }
#pragma unroll
    for (int j = 0; j < 4; ++j) {
      const int br = wn * 64 + j * 16 + l16;
      i32x4 bf = *(const i32x4*)(sB + br * BK + (((quad + (br >> 1)) & 3) << 4));
#pragma unroll
      for (int i = 0; i < 4; ++i)
        acc[i][j] = __builtin_amdgcn_mfma_i32_16x16x64_i8(af[i], bf, acc[i][j], 0, 0, 0);
    }
    __syncthreads();
  }

  float sn[4];
#pragma unroll
  for (int j = 0; j < 4; ++j) sn[j] = swd[n0 + wn * 64 + j * 16 + l16];
#pragma unroll
  for (int i = 0; i < 4; ++i) {
#pragma unroll
    for (int r = 0; r < 4; ++r) {
      const int row = m0 + wm * 64 + i * 16 + quad * 4 + r;
      const float s_m = sh[row];
#pragma unroll
      for (int j = 0; j < 4; ++j) {
        const int col = n0 + wn * 64 + j * 16 + l16;
        out[(size_t)row * N + col] = (float)acc[i][j][r] * s_m * sn[j];
      }
    }
  }
}

extern "C" void kernel_launch(void* const* d_in, const int* in_sizes, int n_in,
                              void* d_out, int out_size, void* d_ws, size_t ws_size,
                              hipStream_t stream) {
  const float* x  = (const float*)d_in[0];   // [2,2048,4096]
  const float* Wg = (const float*)d_in[1];   // [11008,4096]
  const float* Wu = (const float*)d_in[2];   // [11008,4096]
  const float* Wd = (const float*)d_in[3];   // [4096,11008]
  float* out = (float*)d_out;                // [2,2048,4096] f32

  const int M = 4096;   // B*S
  const int D = 4096;
  const int F = 11008;

  // workspace layout (~378 MB total), all offsets 16B-aligned
  uint8_t* ws = (uint8_t*)d_ws;
  size_t off = 0;
  int8_t* xq  = (int8_t*)(ws + off); off += (size_t)M * D;      // 16 MB
  int8_t* wgq = (int8_t*)(ws + off); off += (size_t)F * D;      // 45 MB
  int8_t* wuq = (int8_t*)(ws + off); off += (size_t)F * D;      // 45 MB
  int8_t* wdq = (int8_t*)(ws + off); off += (size_t)D * F;      // 45 MB
  int8_t* hq  = (int8_t*)(ws + off); off += (size_t)M * F;      // 45 MB
  float* hbuf = (float*)(ws + off);  off += (size_t)M * F * 4;  // 180 MB
  float* sx   = (float*)(ws + off);  off += (size_t)M * 4;
  float* swg  = (float*)(ws + off);  off += (size_t)F * 4;
  float* swu  = (float*)(ws + off);  off += (size_t)F * 4;
  float* swd  = (float*)(ws + off);  off += (size_t)D * 4;
  float* sh   = (float*)(ws + off);  off += (size_t)M * 4;

  hipLaunchKernelGGL(quant_rows_kernel, dim3(M), dim3(256), 0, stream,
                     x, xq, sx, D, 127.0f, -128.0f);
  hipLaunchKernelGGL(quant_rows_kernel, dim3(F), dim3(256), 0, stream,
                     Wg, wgq, swg, D, 7.0f, -8.0f);
  hipLaunchKernelGGL(quant_rows_kernel, dim3(F), dim3(256), 0, stream,
                     Wu, wuq, swu, D, 7.0f, -8.0f);
  hipLaunchKernelGGL(quant_rows_kernel, dim3(D), dim3(256), 0, stream,
                     Wd, wdq, swd, F, 7.0f, -8.0f);
  hipLaunchKernelGGL(gemm1_kernel, dim3(F / BN, M / BM), dim3(256), 0, stream,
                     xq, wgq, wuq, sx, swg, swu, hbuf, M, F, D);
  hipLaunchKernelGGL(quant_h_kernel, dim3(M), dim3(256), 0, stream,
                     hbuf, hq, sh, F);
  hipLaunchKernelGGL(gemm2_kernel, dim3(D / BN, M / BM), dim3(256), 0, stream,
                     hq, wdq, sh, swd, out, M, D, F);
}

// Round 3
// 1273.662 us; speedup vs baseline: 2.7953x; 1.0826x over previous
//
#include <hip/hip_runtime.h>
#include <stdint.h>
#include <stddef.h>

// W4A8 fake-quant SwiGLU MLP for MI355X (gfx950).
// Exact-integer reformulation: fake-quant values are int*scale, so every
// matmul is an int8 x int4 integer GEMM (exact in i32/f32) times rank-1 scales.
// GEMMs: mfma_i32_16x16x64_i8, global_load_lds width-16,
// XOR-swizzled LDS (slot = (quad + (row>>1)) & 3) for conflict-free b128 reads.
//
// R1: gemm1 (256,4)->(256,2): accumulator spill eliminated, 2700 -> 527 us.
// R2: XCD swizzle (gemm1 527->499); gemm2 (256,2) was neutral (no spill there).
// R3: (a) gemm2 tile 128x128 -> 128x256: per-K-step MFMA per wave 16->32,
//     K-step-barrier count halves (176k -> 88k, same as gemm1's work shape).
//     acc[4][8]=128 VGPR, same budget as gemm1's accg+accu.
//     (b) merge the 4 independent input-quant launches into one kernel
//     (removes 3 full pipeline drains between tiny memory-bound kernels).

using i32x4 = __attribute__((ext_vector_type(4))) int;

#define BM 128
#define BN 128
#define BN2 256
#define BK 64

__device__ __forceinline__ void gl2lds16(const void* gptr, void* lptr) {
  __builtin_amdgcn_global_load_lds(
      (const __attribute__((address_space(1))) uint32_t*)gptr,
      (__attribute__((address_space(3))) uint32_t*)lptr, 16, 0, 0);
}

// ---------------------------------------------------------------------------
// Merged per-row symmetric fake-quant for all four inputs in ONE launch.
// blockIdx segments: [0,4096) x rows | [4096,15104) Wg | [15104,26112) Wu |
// [26112,30208) Wd. scale = max(absmax/qmax, 1e-8), q = clip(rint(v/scale)).
// ---------------------------------------------------------------------------
__global__ void quant_all_kernel(
    const float* __restrict__ x, const float* __restrict__ Wg,
    const float* __restrict__ Wu, const float* __restrict__ Wd,
    int8_t* __restrict__ xq, int8_t* __restrict__ wgq,
    int8_t* __restrict__ wuq, int8_t* __restrict__ wdq,
    float* __restrict__ sx, float* __restrict__ swg,
    float* __restrict__ swu, float* __restrict__ swd) {
  const int b = blockIdx.x;
  const float* src;
  int8_t* dst;
  float* scales;
  int cols, row;
  float qmax, qmin;
  if (b < 4096) {
    src = x; dst = xq; scales = sx; cols = 4096; row = b;
    qmax = 127.0f; qmin = -128.0f;
  } else if (b < 4096 + 11008) {
    src = Wg; dst = wgq; scales = swg; cols = 4096; row = b - 4096;
    qmax = 7.0f; qmin = -8.0f;
  } else if (b < 4096 + 22016) {
    src = Wu; dst = wuq; scales = swu; cols = 4096; row = b - 15104;
    qmax = 7.0f; qmin = -8.0f;
  } else {
    src = Wd; dst = wdq; scales = swd; cols = 11008; row = b - 26112;
    qmax = 7.0f; qmin = -8.0f;
  }
  const int n4 = cols >> 2;
  const float4* s4 = (const float4*)(src + (size_t)row * cols);
  float amax = 0.0f;
  for (int i = threadIdx.x; i < n4; i += blockDim.x) {
    float4 v = s4[i];
    amax = fmaxf(amax, fmaxf(fmaxf(fabsf(v.x), fabsf(v.y)),
                             fmaxf(fabsf(v.z), fabsf(v.w))));
  }
#pragma unroll
  for (int off = 32; off > 0; off >>= 1)
    amax = fmaxf(amax, __shfl_xor(amax, off, 64));
  __shared__ float wmax[4];
  if ((threadIdx.x & 63) == 0) wmax[threadIdx.x >> 6] = amax;
  __syncthreads();
  const float scale =
      fmaxf(fmaxf(fmaxf(wmax[0], wmax[1]), fmaxf(wmax[2], wmax[3])) / qmax,
            1e-8f);
  if (threadIdx.x == 0) scales[row] = scale;
  char4* d4 = (char4*)(dst + (size_t)row * cols);
  for (int i = threadIdx.x; i < n4; i += blockDim.x) {
    float4 v = s4[i];
    char4 q;
    q.x = (char)(int)fminf(fmaxf(rintf(v.x / scale), qmin), qmax);
    q.y = (char)(int)fminf(fmaxf(rintf(v.y / scale), qmin), qmax);
    q.z = (char)(int)fminf(fmaxf(rintf(v.z / scale), qmin), qmax);
    q.w = (char)(int)fminf(fmaxf(rintf(v.w / scale), qmin), qmax);
    d4[i] = q;
  }
}

// Two-pass per-row quant of h (depends on gemm1 output; separate launch).
__global__ void quant_h_kernel(const float* __restrict__ h,
                               int8_t* __restrict__ hq,
                               float* __restrict__ sh, int cols) {
  const int row = blockIdx.x;
  const int n4 = cols >> 2;
  const float4* s4 = (const float4*)(h + (size_t)row * cols);
  float amax = 0.0f;
  for (int i = threadIdx.x; i < n4; i += blockDim.x) {
    float4 v = s4[i];
    amax = fmaxf(amax, fmaxf(fmaxf(fabsf(v.x), fabsf(v.y)),
                             fmaxf(fabsf(v.z), fabsf(v.w))));
  }
#pragma unroll
  for (int off = 32; off > 0; off >>= 1)
    amax = fmaxf(amax, __shfl_xor(amax, off, 64));
  __shared__ float wmax[4];
  if ((threadIdx.x & 63) == 0) wmax[threadIdx.x >> 6] = amax;
  __syncthreads();
  const float scale =
      fmaxf(fmaxf(fmaxf(wmax[0], wmax[1]), fmaxf(wmax[2], wmax[3])) / 127.0f,
            1e-8f);
  if (threadIdx.x == 0) sh[row] = scale;
  char4* d4 = (char4*)(hq + (size_t)row * cols);
  for (int i = threadIdx.x; i < n4; i += blockDim.x) {
    float4 v = s4[i];
    char4 q;
    q.x = (char)(int)fminf(fmaxf(rintf(v.x / scale), -128.0f), 127.0f);
    q.y = (char)(int)fminf(fmaxf(rintf(v.y / scale), -128.0f), 127.0f);
    q.z = (char)(int)fminf(fmaxf(rintf(v.z / scale), -128.0f), 127.0f);
    q.w = (char)(int)fminf(fmaxf(rintf(v.w / scale), -128.0f), 127.0f);
    d4[i] = q;
  }
}

// Bijective XCD-aware remap of the linear block id (requires nwg % 8 == 0).
__device__ __forceinline__ int xcd_swizzle(int lid, int nwg) {
  const int cpx = nwg >> 3;
  return (lid & 7) * cpx + (lid >> 3);
}

// Fused gate+up GEMM: acc_g = xq @ Wg^T, acc_u = xq @ Wu^T (int32 exact),
// epilogue h = silu(acc_g*sx*swg) * (acc_u*sx*swu) -> hbuf (f32).
__global__ __launch_bounds__(256, 2) void gemm1_kernel(
    const int8_t* __restrict__ xq, const int8_t* __restrict__ wgq,
    const int8_t* __restrict__ wuq, const float* __restrict__ sx,
    const float* __restrict__ swg, const float* __restrict__ swu,
    float* __restrict__ hbuf, int M, int N, int K) {
  __shared__ __align__(16) int8_t sA[BM * BK];
  __shared__ __align__(16) int8_t sBg[BN * BK];
  __shared__ __align__(16) int8_t sBu[BN * BK];

  const int tid = threadIdx.x;
  const int lane = tid & 63;
  const int quad = lane >> 4;
  const int l16 = lane & 15;
  const int wave = tid >> 6;
  const int wm = wave >> 1;
  const int wn = wave & 1;

  const int nwg = gridDim.x * gridDim.y;
  const int lid = xcd_swizzle(blockIdx.y * gridDim.x + blockIdx.x, nwg);
  const int n0 = (lid % gridDim.x) * BN;
  const int m0 = (lid / gridDim.x) * BM;

  i32x4 accg[4][4] = {};
  i32x4 accu[4][4] = {};

  for (int k0 = 0; k0 < K; k0 += BK) {
#pragma unroll
    for (int it = 0; it < 2; ++it) {
      const int c = tid + it * 256;   // 512 16B chunks per 128x64 tile
      const int r = c >> 2;           // tile row
      const int s = c & 3;            // LDS slot within row
      const int kc = ((s - (r >> 1)) & 3) << 4;  // XOR-swizzled source chunk
      gl2lds16(xq  + (size_t)(m0 + r) * K + (k0 + kc), sA  + c * 16);
      gl2lds16(wgq + (size_t)(n0 + r) * K + (k0 + kc), sBg + c * 16);
      gl2lds16(wuq + (size_t)(n0 + r) * K + (k0 + kc), sBu + c * 16);
    }
    __syncthreads();

    i32x4 af[4];
#pragma unroll
    for (int i = 0; i < 4; ++i) {
      const int ar = wm * 64 + i * 16 + l16;
      af[i] = *(const i32x4*)(sA + ar * BK + (((quad + (ar >> 1)) & 3) << 4));
    }
#pragma unroll
    for (int j = 0; j < 4; ++j) {
      const int br = wn * 64 + j * 16 + l16;
      const int bo = br * BK + (((quad + (br >> 1)) & 3) << 4);
      i32x4 bg = *(const i32x4*)(sBg + bo);
      i32x4 bu = *(const i32x4*)(sBu + bo);
#pragma unroll
      for (int i = 0; i < 4; ++i) {
        accg[i][j] = __builtin_amdgcn_mfma_i32_16x16x64_i8(af[i], bg, accg[i][j], 0, 0, 0);
        accu[i][j] = __builtin_amdgcn_mfma_i32_16x16x64_i8(af[i], bu, accu[i][j], 0, 0, 0);
      }
    }
    __syncthreads();
  }

  float sg[4], su[4];
#pragma unroll
  for (int j = 0; j < 4; ++j) {
    const int col = n0 + wn * 64 + j * 16 + l16;
    sg[j] = swg[col];
    su[j] = swu[col];
  }
#pragma unroll
  for (int i = 0; i < 4; ++i) {
#pragma unroll
    for (int r = 0; r < 4; ++r) {
      const int row = m0 + wm * 64 + i * 16 + quad * 4 + r;
      const float s_x = sx[row];
#pragma unroll
      for (int j = 0; j < 4; ++j) {
        const int col = n0 + wn * 64 + j * 16 + l16;
        const float g = (float)accg[i][j][r] * s_x * sg[j];
        const float u = (float)accu[i][j][r] * s_x * su[j];
        hbuf[(size_t)row * N + col] = (g / (1.0f + expf(-g))) * u;  // silu(g)*u
      }
    }
  }
}

// Down-projection GEMM: out = (hq @ Wd^T) * sh[m] * swd[n]
// R3: 128x256 tile. Per-wave output 64x128, acc[4][8] = 128 VGPR (same
// budget as gemm1). 32 MFMA per wave per K-step, matching gemm1's density.
__global__ __launch_bounds__(256, 2) void gemm2_kernel(
    const int8_t* __restrict__ hq, const int8_t* __restrict__ wdq,
    const float* __restrict__ sh, const float* __restrict__ swd,
    float* __restrict__ out, int M, int N, int K) {
  __shared__ __align__(16) int8_t sA[BM * BK];    // 8 KB
  __shared__ __align__(16) int8_t sB[BN2 * BK];   // 16 KB

  const int tid = threadIdx.x;
  const int lane = tid & 63;
  const int quad = lane >> 4;
  const int l16 = lane & 15;
  const int wave = tid >> 6;
  const int wm = wave >> 1;   // 0..1: 64-row group
  const int wn = wave & 1;    // 0..1: 128-col group

  const int nwg = gridDim.x * gridDim.y;
  const int lid = xcd_swizzle(blockIdx.y * gridDim.x + blockIdx.x, nwg);
  const int n0 = (lid % gridDim.x) * BN2;
  const int m0 = (lid / gridDim.x) * BM;

  i32x4 acc[4][8] = {};

  for (int k0 = 0; k0 < K; k0 += BK) {
#pragma unroll
    for (int it = 0; it < 2; ++it) {  // A tile: 512 chunks
      const int c = tid + it * 256;
      const int r = c >> 2;
      const int s = c & 3;
      const int kc = ((s - (r >> 1)) & 3) << 4;
      gl2lds16(hq + (size_t)(m0 + r) * K + (k0 + kc), sA + c * 16);
    }
#pragma unroll
    for (int it = 0; it < 4; ++it) {  // B tile: 1024 chunks (256 rows)
      const int c = tid + it * 256;
      const int r = c >> 2;
      const int s = c & 3;
      const int kc = ((s - (r >> 1)) & 3) << 4;
      gl2lds16(wdq + (size_t)(n0 + r) * K + (k0 + kc), sB + c * 16);
    }
    __syncthreads();

    i32x4 af[4];
#pragma unroll
    for (int i = 0; i < 4; ++i) {
      const int ar = wm * 64 + i * 16 + l16;
      af[i] = *(const i32x4*)(sA + ar * BK + (((quad + (ar >> 1)) & 3) << 4));
    }
#pragma unroll
    for (int j = 0; j < 8; ++j) {
      const int br = wn * 128 + j * 16 + l16;
      i32x4 bf = *(const i32x4*)(sB + br * BK + (((quad + (br >> 1)) & 3) << 4));
#pragma unroll
      for (int i = 0; i < 4; ++i)
        acc[i][j] = __builtin_amdgcn_mfma_i32_16x16x64_i8(af[i], bf, acc[i][j], 0, 0, 0);
    }
    __syncthreads();
  }

  float sn[8];
#pragma unroll
  for (int j = 0; j < 8; ++j) sn[j] = swd[n0 + wn * 128 + j * 16 + l16];
#pragma unroll
  for (int i = 0; i < 4; ++i) {
#pragma unroll
    for (int r = 0; r < 4; ++r) {
      const int row = m0 + wm * 64 + i * 16 + quad * 4 + r;
      const float s_m = sh[row];
#pragma unroll
      for (int j = 0; j < 8; ++j) {
        const int col = n0 + wn * 128 + j * 16 + l16;
        out[(size_t)row * N + col] = (float)acc[i][j][r] * s_m * sn[j];
      }
    }
  }
}

extern "C" void kernel_launch(void* const* d_in, const int* in_sizes, int n_in,
                              void* d_out, int out_size, void* d_ws, size_t ws_size,
                              hipStream_t stream) {
  const float* x  = (const float*)d_in[0];   // [2,2048,4096]
  const float* Wg = (const float*)d_in[1];   // [11008,4096]
  const float* Wu = (const float*)d_in[2];   // [11008,4096]
  const float* Wd = (const float*)d_in[3];   // [4096,11008]
  float* out = (float*)d_out;                // [2,2048,4096] f32

  const int M = 4096;   // B*S
  const int D = 4096;
  const int F = 11008;

  // workspace layout (~378 MB total), all offsets 16B-aligned
  uint8_t* ws = (uint8_t*)d_ws;
  size_t off = 0;
  int8_t* xq  = (int8_t*)(ws + off); off += (size_t)M * D;      // 16 MB
  int8_t* wgq = (int8_t*)(ws + off); off += (size_t)F * D;      // 45 MB
  int8_t* wuq = (int8_t*)(ws + off); off += (size_t)F * D;      // 45 MB
  int8_t* wdq = (int8_t*)(ws + off); off += (size_t)D * F;      // 45 MB
  int8_t* hq  = (int8_t*)(ws + off); off += (size_t)M * F;      // 45 MB
  float* hbuf = (float*)(ws + off);  off += (size_t)M * F * 4;  // 180 MB
  float* sx   = (float*)(ws + off);  off += (size_t)M * 4;
  float* swg  = (float*)(ws + off);  off += (size_t)F * 4;
  float* swu  = (float*)(ws + off);  off += (size_t)F * 4;
  float* swd  = (float*)(ws + off);  off += (size_t)D * 4;
  float* sh   = (float*)(ws + off);  off += (size_t)M * 4;

  // One merged quant launch for x, Wg, Wu, Wd (independent rows).
  hipLaunchKernelGGL(quant_all_kernel, dim3(M + F + F + D), dim3(256), 0,
                     stream, x, Wg, Wu, Wd, xq, wgq, wuq, wdq,
                     sx, swg, swu, swd);
  hipLaunchKernelGGL(gemm1_kernel, dim3(F / BN, M / BM), dim3(256), 0, stream,
                     xq, wgq, wuq, sx, swg, swu, hbuf, M, F, D);
  hipLaunchKernelGGL(quant_h_kernel, dim3(M), dim3(256), 0, stream,
                     hbuf, hq, sh, F);
  hipLaunchKernelGGL(gemm2_kernel, dim3(D / BN2, M / BM), dim3(256), 0, stream,
                     hq, wdq, sh, swd, out, M, D, F);
}